// Round 8
// baseline (1496.530 us; speedup 1.0000x reference)
//
#include <hip/hip_runtime.h>

typedef float f32x4 __attribute__((ext_vector_type(4)));

static constexpr int E_ = 8, M_ = 4096, K_ = 2048, N_ = 2048;
static constexpr int KB_ = 16;           // 128-wide k scale blocks
static constexpr int NB128 = N_ / 128;   // weight n-blocks
static constexpr int BM = 256, BN = 256, BK = 64;
static constexpr int KT = K_ / BK;       // 32 K-tiles
static constexpr int MT2 = M_ / BM;      // 16
static constexpr int NT2 = N_ / BN;      // 8
#define FP8MAX 448.0f

// ---------------- quantize x: one scale per (row, 128-k-block) ----------------
__global__ __launch_bounds__(256) void quant_x_kernel(const float* __restrict__ x,
                                                      unsigned char* __restrict__ qx,
                                                      float* __restrict__ sx) {
  long tile = (long)blockIdx.x * 8 + (threadIdx.x >> 5);
  int lane = threadIdx.x & 31;
  f32x4 v = *(const f32x4*)(x + tile * 128 + lane * 4);
  float am = fmaxf(fmaxf(fabsf(v[0]), fabsf(v[1])), fmaxf(fabsf(v[2]), fabsf(v[3])));
#pragma unroll
  for (int off = 16; off; off >>= 1) am = fmaxf(am, __shfl_xor(am, off, 32));
  float safe = fmaxf(am, 1e-4f);
  float qs = FP8MAX / safe;
  int pk = 0;
  pk = __builtin_amdgcn_cvt_pk_fp8_f32(v[0] * qs, v[1] * qs, pk, false);
  pk = __builtin_amdgcn_cvt_pk_fp8_f32(v[2] * qs, v[3] * qs, pk, true);
  *(int*)(qx + tile * 128 + lane * 4) = pk;
  if (lane == 0) sx[tile] = safe / FP8MAX;
}

// ---------------- quantize w: one scale per 128x128 block ----------------
__global__ __launch_bounds__(256) void quant_w_kernel(const float* __restrict__ w,
                                                      unsigned char* __restrict__ qw,
                                                      float* __restrict__ sw) {
  int b = blockIdx.x;
  int kb = b % KB_;
  int t2 = b / KB_;
  int nb = t2 % NB128;
  int e = t2 / NB128;
  int tid = threadIdx.x;
  int r = tid >> 1;
  int c0 = (tid & 1) * 64;
  const float* base = w + ((long)(e * N_ + nb * 128 + r)) * K_ + kb * 128 + c0;
  f32x4 v[16];
  float am = 0.f;
#pragma unroll
  for (int j = 0; j < 16; ++j) {
    v[j] = *(const f32x4*)(base + j * 4);
    am = fmaxf(am, fmaxf(fmaxf(fabsf(v[j][0]), fabsf(v[j][1])),
                         fmaxf(fabsf(v[j][2]), fabsf(v[j][3]))));
  }
#pragma unroll
  for (int off = 32; off; off >>= 1) am = fmaxf(am, __shfl_xor(am, off, 64));
  __shared__ float red[4];
  if ((tid & 63) == 0) red[tid >> 6] = am;
  __syncthreads();
  am = fmaxf(fmaxf(red[0], red[1]), fmaxf(red[2], red[3]));
  float safe = fmaxf(am, 1e-6f);
  float qs = FP8MAX / safe;
  unsigned char* outp = qw + ((long)(e * N_ + nb * 128 + r)) * K_ + kb * 128 + c0;
#pragma unroll
  for (int j4 = 0; j4 < 4; ++j4) {
    uint4 pkv;
    unsigned int* pp = (unsigned int*)&pkv;
#pragma unroll
    for (int q = 0; q < 4; ++q) {
      int j = j4 * 4 + q;
      int pk = 0;
      pk = __builtin_amdgcn_cvt_pk_fp8_f32(v[j][0] * qs, v[j][1] * qs, pk, false);
      pk = __builtin_amdgcn_cvt_pk_fp8_f32(v[j][2] * qs, v[j][3] * qs, pk, true);
      pp[q] = (unsigned int)pk;
    }
    *(uint4*)(outp + j4 * 16) = pkv;
  }
  if (tid == 0) sw[(e * NB128 + nb) * KB_ + kb] = safe / FP8MAX;
}

// ------ grouped GEMM: 256x256, BK=64, 4 quadrant-phases, counted vmcnt(4) ------
// A-row mapping MH*128 + wr*64 (+mf*16) makes the read partition congruent with
// the 128-row stage units: A-lo reads == rows 0..127, A-hi == rows 128..255.
__device__ inline void gload16(const void* g, void* l) {
  __builtin_amdgcn_global_load_lds(
      (const __attribute__((address_space(1))) unsigned int*)g,
      (__attribute__((address_space(3))) unsigned int*)l, 16, 0, 0);
}

#define BAR __builtin_amdgcn_s_barrier()

// quadrant (mf-half MH, nf-pair NP): 8 independent 2-deep MFMA chains + fold
#define MFMAQ(MH, NP)                                                           \
  do {                                                                          \
    f32x4 p[4][2];                                                              \
    __builtin_amdgcn_s_setprio(1);                                              \
    _Pragma("unroll") for (int mf = 0; mf < 4; ++mf)                            \
      _Pragma("unroll") for (int nf2 = 0; nf2 < 2; ++nf2) {                     \
        f32x4 q = {0.f, 0.f, 0.f, 0.f};                                         \
        q = __builtin_amdgcn_mfma_f32_16x16x32_fp8_fp8(                         \
            af[mf][0], bf[(NP) * 2 + nf2][0], q, 0, 0, 0);                      \
        q = __builtin_amdgcn_mfma_f32_16x16x32_fp8_fp8(                         \
            af[mf][1], bf[(NP) * 2 + nf2][1], q, 0, 0, 0);                      \
        p[mf][nf2] = q;                                                         \
      }                                                                         \
    __builtin_amdgcn_s_setprio(0);                                              \
    _Pragma("unroll") for (int mf = 0; mf < 4; ++mf)                            \
      _Pragma("unroll") for (int nf2 = 0; nf2 < 2; ++nf2)                       \
        _Pragma("unroll") for (int r = 0; r < 4; ++r)                           \
          acc[(MH) * 4 + mf][(NP) * 2 + nf2][r] += p[mf][nf2][r] * sxs[mf][r];  \
  } while (0)

#define RDA(MH)                                                                 \
  _Pragma("unroll") for (int mf = 0; mf < 4; ++mf) {                            \
    const int ra = ((MH) * 128 + wr * 64 + mf * 16 + rl) * BK;                  \
    af[mf][0] = *(const long*)&Acur[ra + cofs[0]];                              \
    af[mf][1] = *(const long*)&Acur[ra + cofs[1]];                              \
  }

#define RDB()                                                                   \
  _Pragma("unroll") for (int nf = 0; nf < 4; ++nf) {                            \
    const int rb = (wc * 64 + nf * 16 + rl) * BK;                               \
    bf[nf][0] = *(const long*)&Bcur[rb + cofs[0]];                              \
    bf[nf][1] = *(const long*)&Bcur[rb + cofs[1]];                              \
  }

#define LDSX(MH)                                                                \
  _Pragma("unroll") for (int mf = 0; mf < 4; ++mf) {                            \
    f32x4 t = *(const f32x4*)&sxl[kb][(MH) * 128 + wr * 64 + mf * 16 + qq * 4]; \
    _Pragma("unroll") for (int j = 0; j < 4; ++j) sxs[mf][j] = t[j] * swk;      \
  }

__global__ __launch_bounds__(512, 2) void gemm_kernel(
    const unsigned char* __restrict__ qx, const unsigned char* __restrict__ qw,
    const float* __restrict__ sx, const float* __restrict__ sw,
    float* __restrict__ out) {
  __shared__ unsigned char As[2][BM * BK];   // 32 KiB
  __shared__ unsigned char Bs[2][BN * BK];   // 32 KiB
  __shared__ float sxl[KB_][BM];             // 16 KiB, [kb][row]
  __shared__ float swl[2][KB_];

  const int e = blockIdx.y;
  const int x = blockIdx.x;
  const int swz = (x & 7) * 16 + (x >> 3);   // bijective: 128 % 8 == 0
  const int mt = swz >> 3, nt = swz & 7;
  const int brow = mt * BM, bcol = nt * BN;

  const int tid = threadIdx.x;
  const int w = tid >> 6, l = tid & 63;
  const int wr = w >> 2, wc = w & 3;         // 2 (M) x 4 (N); 128x64 C per wave
  const int qq = l >> 4, rl = l & 15;
  const int o8 = (qq & 1) * 8, ch = qq >> 1;
  const int rx = rl & 3;

  const unsigned char* Ab = qx + (size_t)(e * M_ + brow) * K_;
  const unsigned char* Bb = qw + (size_t)(e * N_ + bcol) * K_;

  // ---- stage dequant scales into LDS ----
  {
    int row = tid >> 1, h = (tid & 1) * 8;
    const float* sp = sx + (size_t)(e * M_ + brow + row) * KB_ + h;
    f32x4 s0 = *(const f32x4*)sp;
    f32x4 s1 = *(const f32x4*)(sp + 4);
#pragma unroll
    for (int j = 0; j < 4; ++j) {
      sxl[h + j][row] = s0[j];
      sxl[h + 4 + j][row] = s1[j];
    }
    if (tid < 32)
      swl[tid >> 4][tid & 15] =
          sw[(e * NB128 + nt * 2 + (tid >> 4)) * KB_ + (tid & 15)];
  }

  // ---- staging: one call = 512 thr x 16 B = 128 rows x 64 B, linear LDS ----
  auto stageA = [&](int rb, int kt2, int tb) {
    const int row = rb + (w << 4) + (l >> 2);
    gload16(Ab + (size_t)row * K_ + kt2 * BK + (((l & 3) ^ (row & 3)) << 4),
            &As[tb][(rb + (w << 4)) * BK]);
  };
  auto stageB = [&](int rb, int kt2, int tb) {
    const int row = rb + (w << 4) + (l >> 2);
    gload16(Bb + (size_t)row * K_ + kt2 * BK + (((l & 3) ^ (row & 3)) << 4),
            &Bs[tb][(rb + (w << 4)) * BK]);
  };

  // ---- prologue: stage tiles 0,1 (4 loads each); publish tile 0 + scales ----
#pragma unroll
  for (int t = 0; t < 2; ++t) {
    stageA(0, t, t); stageA(128, t, t);
    stageB(0, t, t); stageB(128, t, t);
  }
  asm volatile("s_waitcnt vmcnt(4) lgkmcnt(0)" ::: "memory");
  BAR;
  __builtin_amdgcn_sched_barrier(0);

  f32x4 acc[8][4] = {};
  long af[4][2], bf[4][2];
  f32x4 sxs[4];
  int cofs[2];
#pragma unroll
  for (int ks = 0; ks < 2; ++ks) cofs[ks] = (((ks * 2 + ch) ^ rx) << 4) + o8;

  for (int kt = 0; kt < KT; ++kt) {
    const int buf = kt & 1;
    const unsigned char* Acur = As[buf];
    const unsigned char* Bcur = Bs[buf];
    const int kb = kt >> 1;                 // two K-tiles share one scale block
    const float swk = swl[wc >> 1][kb];

    // P0: read A-lo (rows 0..127) + all B; quadrant (lo, nf01)
    LDSX(0); RDA(0); RDB();
    BAR;
    MFMAQ(0, 0);
    BAR;
    // P1: ALL B reads + A-lo reads sealed by P0's closing BAR -> B units free
    if (kt + 2 < KT) { stageB(0, kt + 2, buf); stageB(128, kt + 2, buf); }
    BAR;
    MFMAQ(0, 1);
    BAR;
    // P2: A-lo unit (rows 0..127) free -> stage; read A-hi (rows 128..255)
    if (kt + 2 < KT) stageA(0, kt + 2, buf);
    RDA(1); LDSX(1);
    BAR;
    MFMAQ(1, 0);
    BAR;
    // P3: A-hi reads sealed by P2's closing BAR -> rows 128..255 free
    if (kt + 2 < KT) stageA(128, kt + 2, buf);
    BAR;
    MFMAQ(1, 1);
    // drain-then-publish tile kt+1 (kt+2's 4 loads stay in flight)
    if (kt < KT - 2)       { asm volatile("s_waitcnt vmcnt(4)" ::: "memory"); }
    else if (kt == KT - 2) { asm volatile("s_waitcnt vmcnt(0)" ::: "memory"); }
    BAR;
    __builtin_amdgcn_sched_barrier(0);
  }

  // ---- epilogue: C row = qq*4 + r, col = rl; acc[MF] row base = (MF>>2)*128 + wr*64 ----
#pragma unroll
  for (int MF = 0; MF < 8; ++MF) {
    const int m = brow + (MF >> 2) * 128 + wr * 64 + (MF & 3) * 16 + qq * 4;
#pragma unroll
    for (int nf = 0; nf < 4; ++nf) {
      const int n = bcol + wc * 64 + nf * 16 + rl;
      float* op = out + (size_t)(e * M_ + m) * N_ + n;
#pragma unroll
      for (int r = 0; r < 4; ++r) op[(size_t)r * N_] = acc[MF][nf][r];
    }
  }
}

extern "C" void kernel_launch(void* const* d_in, const int* in_sizes, int n_in,
                              void* d_out, int out_size, void* d_ws, size_t ws_size,
                              hipStream_t stream) {
  const float* x = (const float*)d_in[0];
  const float* wt = (const float*)d_in[1];
  float* out = (float*)d_out;

  unsigned char* ws = (unsigned char*)d_ws;
  unsigned char* qx = ws;                               // 64 MiB
  unsigned char* qw = ws + (size_t)E_ * M_ * K_;        // 32 MiB
  float* sx = (float*)(qw + (size_t)E_ * N_ * K_);      // 2 MiB
  float* sw = sx + (size_t)E_ * M_ * KB_;               // 8 KiB

  quant_x_kernel<<<dim3((E_ * M_ * KB_) / 8), dim3(256), 0, stream>>>(x, qx, sx);
  quant_w_kernel<<<dim3(E_ * NB128 * KB_), dim3(256), 0, stream>>>(wt, qw, sw);
  gemm_kernel<<<dim3(MT2 * NT2, E_), dim3(512), 0, stream>>>(qx, qw, sx, sw, out);
}

// Round 9
// 422.113 us; speedup vs baseline: 3.5453x; 3.5453x over previous
//
#include <hip/hip_runtime.h>

typedef float f32x4 __attribute__((ext_vector_type(4)));
typedef float f32x2 __attribute__((ext_vector_type(2)));
typedef short s16x8 __attribute__((ext_vector_type(8)));

static constexpr int E_ = 8, M_ = 4096, K_ = 2048, N_ = 2048;
static constexpr int KB_ = 16;           // 128-wide k scale blocks
static constexpr int NB128 = N_ / 128;   // weight n-blocks
#define FP8MAX 448.0f

__device__ inline unsigned short f2bf(float f) {   // RNE f32->bf16 (finite inputs)
  unsigned u = __builtin_bit_cast(unsigned, f);
  return (unsigned short)((u + 0x7FFFu + ((u >> 16) & 1u)) >> 16);
}

// ============ PRIMARY PATH: dequant folded to bf16 at quant time ============

__global__ __launch_bounds__(256) void quant_x_bf16(const float* __restrict__ x,
                                                    unsigned short* __restrict__ qxb) {
  long tile = (long)blockIdx.x * 8 + (threadIdx.x >> 5);
  int lane = threadIdx.x & 31;
  f32x4 v = *(const f32x4*)(x + tile * 128 + lane * 4);
  float am = fmaxf(fmaxf(fabsf(v[0]), fabsf(v[1])), fmaxf(fabsf(v[2]), fabsf(v[3])));
#pragma unroll
  for (int off = 16; off; off >>= 1) am = fmaxf(am, __shfl_xor(am, off, 32));
  float safe = fmaxf(am, 1e-4f);
  float qs = FP8MAX / safe, ds = safe / FP8MAX;
  int pk = 0;
  pk = __builtin_amdgcn_cvt_pk_fp8_f32(v[0] * qs, v[1] * qs, pk, false);
  pk = __builtin_amdgcn_cvt_pk_fp8_f32(v[2] * qs, v[3] * qs, pk, true);
  f32x2 lo = __builtin_amdgcn_cvt_pk_f32_fp8(pk, false);
  f32x2 hi = __builtin_amdgcn_cvt_pk_f32_fp8(pk, true);
  ushort4 o;
  o.x = f2bf(lo[0] * ds); o.y = f2bf(lo[1] * ds);
  o.z = f2bf(hi[0] * ds); o.w = f2bf(hi[1] * ds);
  *(ushort4*)(qxb + tile * 128 + lane * 4) = o;
}

__global__ __launch_bounds__(256) void quant_w_bf16(const float* __restrict__ w,
                                                    unsigned short* __restrict__ qwb) {
  int b = blockIdx.x;
  int kb = b % KB_;
  int t2 = b / KB_;
  int nb = t2 % NB128;
  int e = t2 / NB128;
  int tid = threadIdx.x;
  int r = tid >> 1;
  int c0 = (tid & 1) * 64;
  const float* base = w + ((long)(e * N_ + nb * 128 + r)) * K_ + kb * 128 + c0;
  f32x4 v[16];
  float am = 0.f;
#pragma unroll
  for (int j = 0; j < 16; ++j) {
    v[j] = *(const f32x4*)(base + j * 4);
    am = fmaxf(am, fmaxf(fmaxf(fabsf(v[j][0]), fabsf(v[j][1])),
                         fmaxf(fabsf(v[j][2]), fabsf(v[j][3]))));
  }
#pragma unroll
  for (int off = 32; off; off >>= 1) am = fmaxf(am, __shfl_xor(am, off, 64));
  __shared__ float red[4];
  if ((tid & 63) == 0) red[tid >> 6] = am;
  __syncthreads();
  am = fmaxf(fmaxf(red[0], red[1]), fmaxf(red[2], red[3]));
  float safe = fmaxf(am, 1e-6f);
  float qs = FP8MAX / safe, ds = safe / FP8MAX;
  unsigned short* outp = qwb + ((long)(e * N_ + nb * 128 + r)) * K_ + kb * 128 + c0;
#pragma unroll
  for (int j2 = 0; j2 < 8; ++j2) {   // two f32x4 -> 8 bf16 = one 16B store
    ushort4 o[2];
#pragma unroll
    for (int h = 0; h < 2; ++h) {
      int j = j2 * 2 + h;
      int pk = 0;
      pk = __builtin_amdgcn_cvt_pk_fp8_f32(v[j][0] * qs, v[j][1] * qs, pk, false);
      pk = __builtin_amdgcn_cvt_pk_fp8_f32(v[j][2] * qs, v[j][3] * qs, pk, true);
      f32x2 lo = __builtin_amdgcn_cvt_pk_f32_fp8(pk, false);
      f32x2 hi = __builtin_amdgcn_cvt_pk_f32_fp8(pk, true);
      o[h].x = f2bf(lo[0] * ds); o[h].y = f2bf(lo[1] * ds);
      o[h].z = f2bf(hi[0] * ds); o[h].w = f2bf(hi[1] * ds);
    }
    ushort4* dst = (ushort4*)(outp + j2 * 8);
    dst[0] = o[0]; dst[1] = o[1];
  }
}

// ---- plain bf16 grouped GEMM: 256x256, BK=64 elems (128B rows), 4 phases ----
__device__ inline void gload16(const void* g, void* l) {
  __builtin_amdgcn_global_load_lds(
      (const __attribute__((address_space(1))) unsigned int*)g,
      (__attribute__((address_space(3))) unsigned int*)l, 16, 0, 0);
}

#define BAR __builtin_amdgcn_s_barrier()

// 16 MFMA cluster: 8 independent 2-chains, direct C-operand accumulation
#define QUAD(AV, BV, MO, NO)                                                    \
  do {                                                                          \
    __builtin_amdgcn_s_setprio(1);                                              \
    _Pragma("unroll") for (int mf = 0; mf < 4; ++mf)                            \
      _Pragma("unroll") for (int nf = 0; nf < 2; ++nf) {                        \
        acc[(MO) + mf][(NO) + nf] = __builtin_amdgcn_mfma_f32_16x16x32_bf16(    \
            AV[mf][0], BV[nf][0], acc[(MO) + mf][(NO) + nf], 0, 0, 0);          \
        acc[(MO) + mf][(NO) + nf] = __builtin_amdgcn_mfma_f32_16x16x32_bf16(    \
            AV[mf][1], BV[nf][1], acc[(MO) + mf][(NO) + nf], 0, 0, 0);          \
      }                                                                         \
    __builtin_amdgcn_s_setprio(0);                                              \
  } while (0)

static constexpr int GKT = 32;   // K tiles of 64 elems

__global__ __launch_bounds__(512, 2) void gemm_bf16(
    const unsigned short* __restrict__ qxb, const unsigned short* __restrict__ qwb,
    float* __restrict__ out) {
  __shared__ unsigned char As[2][256 * 128];   // 64 KiB (rows x 128B)
  __shared__ unsigned char Bs[2][256 * 128];   // 64 KiB

  const int e = blockIdx.y;
  const int x = blockIdx.x;
  const int swz = (x & 7) * 16 + (x >> 3);     // bijective: 128 % 8 == 0
  const int mt = swz >> 3, nt = swz & 7;
  const int brow = mt * 256, bcol = nt * 256;

  const int tid = threadIdx.x;
  const int w = tid >> 6, l = tid & 63;
  const int wr = w >> 2, wc = w & 3;           // 2 (M) x 4 (N); 128x64 C per wave
  const int qq = l >> 4, rl = l & 15;

  const unsigned char* Ab = (const unsigned char*)(qxb + (size_t)(e * M_ + brow) * K_);
  const unsigned char* Bb = (const unsigned char*)(qwb + (size_t)(e * N_ + bcol) * K_);

  // staging: one call = 64 rows x 128B (512 thr x 16B); wave w rows +w*8
  const int gsw = (((l & 7) ^ ((l >> 3) & 7)) << 4);   // pre-swizzled src chunk
  auto stA = [&](int u, int t2, int tb) {
    const int r = u * 64 + w * 8 + (l >> 3);
    gload16(Ab + (size_t)r * (K_ * 2) + t2 * 128 + gsw, &As[tb][(u * 64 + w * 8) * 128]);
  };
  auto stB = [&](int u, int t2, int tb) {
    const int r = u * 64 + w * 8 + (l >> 3);
    gload16(Bb + (size_t)r * (K_ * 2) + t2 * 128 + gsw, &Bs[tb][(u * 64 + w * 8) * 128]);
  };

  // prologue: fully stage tiles 0,1 (8 calls each); publish tile 0
#pragma unroll
  for (int t = 0; t < 2; ++t) {
    stA(0, t, t); stA(1, t, t); stA(2, t, t); stA(3, t, t);
    stB(0, t, t); stB(1, t, t); stB(2, t, t); stB(3, t, t);
  }
  asm volatile("s_waitcnt vmcnt(8)" ::: "memory");
  BAR;
  __builtin_amdgcn_sched_barrier(0);

  f32x4 acc[8][4] = {};
  int cofs[2];
#pragma unroll
  for (int ks = 0; ks < 2; ++ks) cofs[ks] = (((ks * 4 + qq) ^ (rl & 7)) << 4);
  const int aro = wr * 64 + rl;   // A row (+ MH*128 + mf*16); row&7 == rl&7
  const int bro = wc * 64 + rl;   // B row (+ NP*32 + nf*16)

  s16x8 af[4][2], ag[4][2], bf[2][2], bg[2][2];

  for (int kt = 0; kt < GKT; ++kt) {
    const int buf = kt & 1;
    const unsigned char* Acur = As[buf];
    const unsigned char* Bcur = Bs[buf];

    // P0: read A-lo (rows 0..127) + B-q0; MFMA quadrant (lo, n0)
#pragma unroll
    for (int mf = 0; mf < 4; ++mf)
#pragma unroll
      for (int ks = 0; ks < 2; ++ks)
        af[mf][ks] = *(const s16x8*)&Acur[(aro + mf * 16) * 128 + cofs[ks]];
#pragma unroll
    for (int nf = 0; nf < 2; ++nf)
#pragma unroll
      for (int ks = 0; ks < 2; ++ks)
        bf[nf][ks] = *(const s16x8*)&Bcur[(bro + nf * 16) * 128 + cofs[ks]];
    BAR;
    QUAD(af, bf, 0, 0);
    BAR;
    // P1: A-lo reads sealed -> stage units 0,1; read B-q1
    if (kt + 2 < GKT) { stA(0, kt + 2, buf); stA(1, kt + 2, buf); }
#pragma unroll
    for (int nf = 0; nf < 2; ++nf)
#pragma unroll
      for (int ks = 0; ks < 2; ++ks)
        bg[nf][ks] = *(const s16x8*)&Bcur[(bro + 32 + nf * 16) * 128 + cofs[ks]];
    BAR;
    QUAD(af, bg, 0, 2);
    BAR;
    // P2: ALL B reads sealed by P1's close-BAR -> stage B; read A-hi
    if (kt + 2 < GKT) { stB(0, kt + 2, buf); stB(1, kt + 2, buf);
                        stB(2, kt + 2, buf); stB(3, kt + 2, buf); }
#pragma unroll
    for (int mf = 0; mf < 4; ++mf)
#pragma unroll
      for (int ks = 0; ks < 2; ++ks)
        ag[mf][ks] = *(const s16x8*)&Acur[(aro + 128 + mf * 16) * 128 + cofs[ks]];
    BAR;
    QUAD(ag, bf, 4, 0);
    BAR;
    // P3: A-hi reads sealed -> stage units 2,3; MFMA (hi, n1) pure-reg
    if (kt + 2 < GKT) { stA(2, kt + 2, buf); stA(3, kt + 2, buf); }
    BAR;
    QUAD(ag, bg, 4, 2);
    // drain-then-publish tile kt+1 (kt+2's 8 loads stay in flight)
    if (kt < GKT - 2)       { asm volatile("s_waitcnt vmcnt(8)" ::: "memory"); }
    else if (kt == GKT - 2) { asm volatile("s_waitcnt vmcnt(0)" ::: "memory"); }
    BAR;
    __builtin_amdgcn_sched_barrier(0);
  }

  // epilogue: C row = qq*4 + r, col = rl (validated rounds 1-8)
#pragma unroll
  for (int MF = 0; MF < 8; ++MF) {
    const int m = brow + (MF >> 2) * 128 + wr * 64 + (MF & 3) * 16 + qq * 4;
#pragma unroll
    for (int nfq = 0; nfq < 4; ++nfq) {
      const int n = bcol + wc * 64 + (nfq >> 1) * 32 + (nfq & 1) * 16 + rl;
      float* op = out + (size_t)(e * M_ + m) * N_ + n;
#pragma unroll
      for (int r = 0; r < 4; ++r) op[(size_t)r * N_] = acc[MF][nfq][r];
    }
  }
}

// ============ FALLBACK PATH (round-1 validated, ~404 us) ============

__global__ __launch_bounds__(256) void quant_x_fb(const float* __restrict__ x,
                                                  unsigned char* __restrict__ qx,
                                                  float* __restrict__ sx) {
  long tile = (long)blockIdx.x * 8 + (threadIdx.x >> 5);
  int lane = threadIdx.x & 31;
  f32x4 v = *(const f32x4*)(x + tile * 128 + lane * 4);
  float am = fmaxf(fmaxf(fabsf(v[0]), fabsf(v[1])), fmaxf(fabsf(v[2]), fabsf(v[3])));
#pragma unroll
  for (int off = 16; off; off >>= 1) am = fmaxf(am, __shfl_xor(am, off, 32));
  float safe = fmaxf(am, 1e-4f);
  float qs = FP8MAX / safe;
  int pk = 0;
  pk = __builtin_amdgcn_cvt_pk_fp8_f32(v[0] * qs, v[1] * qs, pk, false);
  pk = __builtin_amdgcn_cvt_pk_fp8_f32(v[2] * qs, v[3] * qs, pk, true);
  *(int*)(qx + tile * 128 + lane * 4) = pk;
  if (lane == 0) sx[tile] = safe / FP8MAX;
}

__global__ __launch_bounds__(256) void quant_w_fb(const float* __restrict__ w,
                                                  unsigned char* __restrict__ qw,
                                                  float* __restrict__ sw) {
  int b = blockIdx.x;
  int kb = b % KB_;
  int t2 = b / KB_;
  int nb = t2 % NB128;
  int e = t2 / NB128;
  int tid = threadIdx.x;
  int r = tid >> 1;
  int c0 = (tid & 1) * 64;
  const float* base = w + ((long)(e * N_ + nb * 128 + r)) * K_ + kb * 128 + c0;
  f32x4 v[16];
  float am = 0.f;
#pragma unroll
  for (int j = 0; j < 16; ++j) {
    v[j] = *(const f32x4*)(base + j * 4);
    am = fmaxf(am, fmaxf(fmaxf(fabsf(v[j][0]), fabsf(v[j][1])),
                         fmaxf(fabsf(v[j][2]), fabsf(v[j][3]))));
  }
#pragma unroll
  for (int off = 32; off; off >>= 1) am = fmaxf(am, __shfl_xor(am, off, 64));
  __shared__ float red[4];
  if ((tid & 63) == 0) red[tid >> 6] = am;
  __syncthreads();
  am = fmaxf(fmaxf(red[0], red[1]), fmaxf(red[2], red[3]));
  float safe = fmaxf(am, 1e-6f);
  float qs = FP8MAX / safe;
  unsigned char* outp = qw + ((long)(e * N_ + nb * 128 + r)) * K_ + kb * 128 + c0;
#pragma unroll
  for (int j4 = 0; j4 < 4; ++j4) {
    uint4 pkv;
    unsigned int* pp = (unsigned int*)&pkv;
#pragma unroll
    for (int q = 0; q < 4; ++q) {
      int j = j4 * 4 + q;
      int pk = 0;
      pk = __builtin_amdgcn_cvt_pk_fp8_f32(v[j][0] * qs, v[j][1] * qs, pk, false);
      pk = __builtin_amdgcn_cvt_pk_fp8_f32(v[j][2] * qs, v[j][3] * qs, pk, true);
      pp[q] = (unsigned int)pk;
    }
    *(uint4*)(outp + j4 * 16) = pkv;
  }
  if (tid == 0) sw[(e * NB128 + nb) * KB_ + kb] = safe / FP8MAX;
}

__global__ __launch_bounds__(256, 2) void gemm_fb(
    const unsigned char* __restrict__ qx, const unsigned char* __restrict__ qw,
    const float* __restrict__ sx, const float* __restrict__ sw,
    float* __restrict__ out) {
  __shared__ unsigned char Asf[128 * 128];
  __shared__ unsigned char Bsf[128 * 128];
  __shared__ float sxl[128][17];
  __shared__ float swl[16];

  const int NTf = N_ / 128;
  const int e = blockIdx.y;
  const int mt = blockIdx.x / NTf;
  const int nt = blockIdx.x % NTf;
  const int brow = mt * 128, bcol = nt * 128;
  const int tid = threadIdx.x;
  const int w = tid >> 6, l = tid & 63;
  const int wr = w >> 1, wc = w & 1;
  const int qq = l >> 4, rl = l & 15;

  {
    int row = tid >> 1, half = (tid & 1) * 8;
    const float* sp = sx + ((long)(e * M_ + brow + row)) * KB_ + half;
    f32x4 s0 = *(const f32x4*)sp;
    f32x4 s1 = *(const f32x4*)(sp + 4);
#pragma unroll
    for (int j = 0; j < 4; ++j) {
      sxl[row][half + j] = s0[j];
      sxl[row][half + 4 + j] = s1[j];
    }
    if (tid < KB_) swl[tid] = sw[(e * NTf + nt) * KB_ + tid];
  }

  f32x4 acc[4][4] = {};
  const unsigned char* Ab = qx + (long)(e * M_ + brow) * K_;
  const unsigned char* Bb = qw + (long)(e * N_ + bcol) * K_;
  const int lr8 = l >> 3, lc8 = l & 7;
  const int sch = (lc8 ^ lr8) * 16;
  const int o8 = (qq & 1) * 8;
  const int ch = qq >> 1;

  for (int kb = 0; kb < KB_; ++kb) {
    __syncthreads();
#pragma unroll
    for (int i = 0; i < 4; ++i) {
      const int rt = i * 32 + w * 8;
      gload16(Ab + (long)(rt + lr8) * K_ + kb * 128 + sch, Asf + rt * 128);
      gload16(Bb + (long)(rt + lr8) * K_ + kb * 128 + sch, Bsf + rt * 128);
    }
    __syncthreads();

    long af[4][4], bfr[4][4];
#pragma unroll
    for (int f = 0; f < 4; ++f) {
      const int ra = wr * 64 + f * 16 + rl;
      const int rb = wc * 64 + f * 16 + rl;
      const int rxa = ra & 7, rxb = rb & 7;
#pragma unroll
      for (int ks = 0; ks < 4; ++ks) {
        const int c = ks * 2 + ch;
        af[f][ks] = *(const long*)(Asf + ra * 128 + ((c ^ rxa) * 16) + o8);
        bfr[f][ks] = *(const long*)(Bsf + rb * 128 + ((c ^ rxb) * 16) + o8);
      }
    }

    const float swk = swl[kb];
    float sxs[4][4];
#pragma unroll
    for (int mf = 0; mf < 4; ++mf)
#pragma unroll
      for (int r = 0; r < 4; ++r)
        sxs[mf][r] = sxl[wr * 64 + mf * 16 + qq * 4 + r][kb] * swk;

#pragma unroll
    for (int mf = 0; mf < 4; ++mf)
#pragma unroll
      for (int nf = 0; nf < 4; ++nf) {
        f32x4 p = {0.f, 0.f, 0.f, 0.f};
#pragma unroll
        for (int ks = 0; ks < 4; ++ks)
          p = __builtin_amdgcn_mfma_f32_16x16x32_fp8_fp8(af[mf][ks], bfr[nf][ks], p, 0, 0, 0);
#pragma unroll
        for (int r = 0; r < 4; ++r) acc[mf][nf][r] += p[r] * sxs[mf][r];
      }
  }

#pragma unroll
  for (int mf = 0; mf < 4; ++mf) {
    const int m = brow + wr * 64 + mf * 16 + qq * 4;
#pragma unroll
    for (int nf = 0; nf < 4; ++nf) {
      const int n = bcol + wc * 64 + nf * 16 + rl;
      float* op = out + ((long)(e * M_ + m)) * N_ + n;
#pragma unroll
      for (int r = 0; r < 4; ++r) op[(long)r * N_] = acc[mf][nf][r];
    }
  }
}

extern "C" void kernel_launch(void* const* d_in, const int* in_sizes, int n_in,
                              void* d_out, int out_size, void* d_ws, size_t ws_size,
                              hipStream_t stream) {
  const float* x = (const float*)d_in[0];
  const float* wt = (const float*)d_in[1];
  float* out = (float*)d_out;

  const size_t needed = ((size_t)E_ * M_ * K_ + (size_t)E_ * N_ * K_) * 2;  // 192 MiB
  if (ws_size >= needed) {
    unsigned short* qxb = (unsigned short*)d_ws;                 // 128 MiB bf16
    unsigned short* qwb = qxb + (size_t)E_ * M_ * K_;            //  64 MiB bf16
    quant_x_bf16<<<dim3((E_ * M_ * KB_) / 8), dim3(256), 0, stream>>>(x, qxb);
    quant_w_bf16<<<dim3(E_ * NB128 * KB_), dim3(256), 0, stream>>>(wt, qwb);
    gemm_bf16<<<dim3((M_ / 256) * (N_ / 256), E_), dim3(512), 0, stream>>>(qxb, qwb, out);
  } else {
    unsigned char* ws = (unsigned char*)d_ws;
    unsigned char* qx = ws;                               // 64 MiB
    unsigned char* qw = ws + (size_t)E_ * M_ * K_;        // 32 MiB
    float* sx = (float*)(qw + (size_t)E_ * N_ * K_);      // 2 MiB
    float* sw = sx + (size_t)E_ * M_ * KB_;               // 8 KiB
    quant_x_fb<<<dim3((E_ * M_ * KB_) / 8), dim3(256), 0, stream>>>(x, qx, sx);
    quant_w_fb<<<dim3(E_ * NB128 * KB_), dim3(256), 0, stream>>>(wt, qw, sw);
    gemm_fb<<<dim3((M_ / 128) * (N_ / 128), E_), dim3(256), 0, stream>>>(qx, qw, sx, sw, out);
  }
}